// Round 2
// baseline (517.381 us; speedup 1.0000x reference)
//
#include <hip/hip_runtime.h>

typedef unsigned short u16;
typedef __attribute__((ext_vector_type(8))) short    s16x8;
typedef __attribute__((ext_vector_type(8))) unsigned short u16x8;
typedef __attribute__((ext_vector_type(4))) float    f32x4;

typedef __attribute__((address_space(1))) const void gvoid_c;
typedef __attribute__((address_space(3))) void       lvoid;

__device__ __forceinline__ float b2f(u16 x) {
    return __builtin_bit_cast(float, (unsigned)x << 16);
}
__device__ __forceinline__ u16 f2bf(float f) {
    unsigned u = __builtin_bit_cast(unsigned, f);
    return (u16)((u + 0x7FFFu + ((u >> 16) & 1u)) >> 16);
}
__device__ __forceinline__ void gld16(const void* g, void* l) {
    __builtin_amdgcn_global_load_lds((gvoid_c*)g, (lvoid*)l, 16, 0, 0);
}

// ---------- transpose + f32->bf16: in f32[R][C] -> out bf16[C][R] ----------
__global__ __launch_bounds__(256) void transpose_f2b(
    const float* __restrict__ in, u16* __restrict__ out, int R, int C)
{
    __shared__ u16 tile[32][33];
    int tx = threadIdx.x & 31, ty = threadIdx.x >> 5;  // 32 x 8
    int c0 = blockIdx.x * 32, r0 = blockIdx.y * 32;
#pragma unroll
    for (int i = 0; i < 32; i += 8)
        tile[ty + i][tx] = f2bf(in[(size_t)(r0 + ty + i) * C + c0 + tx]);
    __syncthreads();
#pragma unroll
    for (int i = 0; i < 32; i += 8)
        out[(size_t)(c0 + ty + i) * R + r0 + tx] = tile[tx][ty + i];
}

// ---------- bias concat [bq|bk|bv] (f32) ----------
__global__ void concat3(const float* a, const float* b, const float* c, float* o) {
    int i = blockIdx.x * blockDim.x + threadIdx.x;  // 3072
    o[i] = (i < 1024) ? a[i] : (i < 2048 ? b[i - 1024] : c[i - 2048]);
}

// ---------- LayerNorm: wave per row, D=1024; f32 in, bf16 out ----------
__global__ __launch_bounds__(256) void ln_k(
    const float* __restrict__ in, const float* __restrict__ gg,
    const float* __restrict__ bb, u16* __restrict__ out)
{
    const int D = 1024;
    int row  = blockIdx.x * 4 + (threadIdx.x >> 6);
    int lane = threadIdx.x & 63;
    const float* ip = in + (size_t)row * D;
    float v[16];
#pragma unroll
    for (int cc = 0; cc < 4; cc++) {
        f32x4 t = *(const f32x4*)(ip + cc * 256 + lane * 4);
#pragma unroll
        for (int i = 0; i < 4; i++) v[cc * 4 + i] = t[i];
    }
    float s1 = 0.f, s2 = 0.f;
#pragma unroll
    for (int i = 0; i < 16; i++) { s1 += v[i]; s2 += v[i] * v[i]; }
#pragma unroll
    for (int m = 1; m < 64; m <<= 1) { s1 += __shfl_xor(s1, m); s2 += __shfl_xor(s2, m); }
    float mu   = s1 * (1.f / 1024.f);
    float var  = s2 * (1.f / 1024.f) - mu * mu;
    float rstd = rsqrtf(var + 1e-5f);
#pragma unroll
    for (int cc = 0; cc < 4; cc++) {
        int e = cc * 256 + lane * 4;
        f32x4 gv = *(const f32x4*)(gg + e);
        f32x4 bv = *(const f32x4*)(bb + e);
        u16 o[4];
#pragma unroll
        for (int i = 0; i < 4; i++)
            o[i] = f2bf((v[cc * 4 + i] - mu) * rstd * gv[i] + bv[i]);
        *(__attribute__((ext_vector_type(4))) unsigned short*)(out + (size_t)row * D + e) =
            (__attribute__((ext_vector_type(4))) unsigned short){o[0], o[1], o[2], o[3]};
    }
}

// ---------- GEMM: C[M,N] = A[M,K](bf16) @ Bt[N,K]^T(bf16) + bias(f32) ----------
// RES: 0 none, 2 f32 residual. OUTF32: store f32 else bf16.
template <int RES, bool RELU, bool OUTF32>
__global__ __launch_bounds__(256) void gemm_bt(
    const u16* __restrict__ A, const u16* __restrict__ Bt,
    const float* __restrict__ bias, const float* __restrict__ res,
    void* __restrict__ out, int M, int N, int K)
{
    __shared__ u16 As[4096];  // [128][32]
    __shared__ u16 Bs[4096];
    int tid = threadIdx.x, wave = tid >> 6, lane = tid & 63;
    int g = lane >> 4, c = lane & 15;
    int wm = wave >> 1, wn = wave & 1;
    int m0 = blockIdx.y * 128, n0 = blockIdx.x * 128;

    f32x4 acc[4][4];
#pragma unroll
    for (int m = 0; m < 4; m++)
#pragma unroll
        for (int n = 0; n < 4; n++) acc[m][n] = (f32x4){0, 0, 0, 0};

    int ch0 = wave * 128 + lane, ch1 = ch0 + 64;
    const u16* Ag0 = A  + (size_t)(m0 + (ch0 >> 2)) * K + (ch0 & 3) * 8;
    const u16* Ag1 = A  + (size_t)(m0 + (ch1 >> 2)) * K + (ch1 & 3) * 8;
    const u16* Bg0 = Bt + (size_t)(n0 + (ch0 >> 2)) * K + (ch0 & 3) * 8;
    const u16* Bg1 = Bt + (size_t)(n0 + (ch1 >> 2)) * K + (ch1 & 3) * 8;
    u16* Al0 = &As[wave * 1024];
    u16* Al1 = &As[wave * 1024 + 512];
    u16* Bl0 = &Bs[wave * 1024];
    u16* Bl1 = &Bs[wave * 1024 + 512];

    for (int k0 = 0; k0 < K; k0 += 32) {
        __syncthreads();
        gld16(Ag0, Al0); gld16(Ag1, Al1);
        gld16(Bg0, Bl0); gld16(Bg1, Bl1);
        Ag0 += 32; Ag1 += 32; Bg0 += 32; Bg1 += 32;
        __syncthreads();
        s16x8 af[4], bfr[4];
#pragma unroll
        for (int m = 0; m < 4; m++)
            af[m] = *(const s16x8*)&As[(wm * 64 + m * 16 + c) * 32 + g * 8];
#pragma unroll
        for (int n = 0; n < 4; n++)
            bfr[n] = *(const s16x8*)&Bs[(wn * 64 + n * 16 + c) * 32 + g * 8];
#pragma unroll
        for (int m = 0; m < 4; m++)
#pragma unroll
            for (int n = 0; n < 4; n++)
                acc[m][n] = __builtin_amdgcn_mfma_f32_16x16x32_bf16(af[m], bfr[n], acc[m][n], 0, 0, 0);
    }

#pragma unroll
    for (int n = 0; n < 4; n++) {
        int col = n0 + wn * 64 + n * 16 + c;
        float bb = bias[col];
#pragma unroll
        for (int m = 0; m < 4; m++) {
#pragma unroll
            for (int j = 0; j < 4; j++) {
                int row = m0 + wm * 64 + m * 16 + g * 4 + j;
                float v = acc[m][n][j] + bb;
                if (RES == 2) v += res[(size_t)row * N + col];
                if (RELU) v = fmaxf(v, 0.f);
                if (OUTF32) ((float*)out)[(size_t)row * N + col] = v;
                else        ((u16*)out)[(size_t)row * N + col] = f2bf(v);
            }
        }
    }
}

// ---------- flash attention (causal), qkv bf16 [token][3072] ----------
__global__ __launch_bounds__(256) void attn_fwd(
    const u16* __restrict__ qkv, u16* __restrict__ o)
{
    const int S = 2048, NC = 3072;
    __shared__ u16 Vt[64][72];        // [d][kv]
    __shared__ u16 Plds[4][16][72];   // per-wave P
    int bh = blockIdx.y, b = bh >> 4, h = bh & 15;
    int qt = blockIdx.x;
    int wave = threadIdx.x >> 6, lane = threadIdx.x & 63;
    int g = lane >> 4, c = lane & 15;
    int q0 = qt * 64 + wave * 16;

    const u16* qp = qkv + (size_t)(b * S + q0 + c) * NC + h * 64;
    s16x8 qf0 = *(const s16x8*)(qp + g * 8);
    s16x8 qf1 = *(const s16x8*)(qp + 32 + g * 8);
    const u16* kb = qkv + (size_t)b * S * NC + 1024 + h * 64;
    const u16* vb = qkv + (size_t)b * S * NC + 2048 + h * 64;

    float mr[4], lr[4];
    f32x4 acc[4];
#pragma unroll
    for (int j = 0; j < 4; j++) { mr[j] = -1e30f; lr[j] = 0.f; }
#pragma unroll
    for (int n = 0; n < 4; n++) acc[n] = (f32x4){0, 0, 0, 0};

    int ntiles = qt + 1;
    int vtt = threadIdx.x >> 2, vcb = (threadIdx.x & 3) * 16;

    for (int t = 0; t < ntiles; t++) {
        int t0 = t * 64;
        __syncthreads();  // protect Vt readers of previous tile
        {   // stage V^T cooperatively
            const u16* vp = vb + (size_t)(t0 + vtt) * NC + vcb;
            u16x8 v0 = *(const u16x8*)vp;
            u16x8 v1 = *(const u16x8*)(vp + 8);
#pragma unroll
            for (int i = 0; i < 8; i++) { Vt[vcb + i][vtt] = v0[i]; Vt[vcb + 8 + i][vtt] = v1[i]; }
        }
        __syncthreads();

        // QK^T
        f32x4 s[4];
#pragma unroll
        for (int kt = 0; kt < 4; kt++) {
            const u16* kp = kb + (size_t)(t0 + kt * 16 + c) * NC + g * 8;
            s16x8 kf0 = *(const s16x8*)kp;
            s16x8 kf1 = *(const s16x8*)(kp + 32);
            f32x4 sv = (f32x4){0, 0, 0, 0};
            sv = __builtin_amdgcn_mfma_f32_16x16x32_bf16(qf0, kf0, sv, 0, 0, 0);
            sv = __builtin_amdgcn_mfma_f32_16x16x32_bf16(qf1, kf1, sv, 0, 0, 0);
            s[kt] = sv;
        }
        // scale + causal mask
#pragma unroll
        for (int kt = 0; kt < 4; kt++) {
            int kcol = t0 + kt * 16 + c;
#pragma unroll
            for (int j = 0; j < 4; j++) {
                int qrow = q0 + g * 4 + j;
                s[kt][j] = (kcol <= qrow) ? s[kt][j] * 0.125f : -1e30f;
            }
        }
        // online softmax (16-lane row groups)
#pragma unroll
        for (int j = 0; j < 4; j++) {
            float tm = fmaxf(fmaxf(s[0][j], s[1][j]), fmaxf(s[2][j], s[3][j]));
#pragma unroll
            for (int m = 1; m < 16; m <<= 1) tm = fmaxf(tm, __shfl_xor(tm, m));
            float mnew = fmaxf(mr[j], tm);
            float corr = __expf(mr[j] - mnew);
            float rs = 0.f;
#pragma unroll
            for (int kt = 0; kt < 4; kt++) { float p = __expf(s[kt][j] - mnew); s[kt][j] = p; rs += p; }
#pragma unroll
            for (int m = 1; m < 16; m <<= 1) rs += __shfl_xor(rs, m);
            lr[j] = lr[j] * corr + rs;
            mr[j] = mnew;
#pragma unroll
            for (int n = 0; n < 4; n++) acc[n][j] *= corr;
        }
        // P -> LDS (bf16)
#pragma unroll
        for (int kt = 0; kt < 4; kt++)
#pragma unroll
            for (int j = 0; j < 4; j++)
                Plds[wave][g * 4 + j][kt * 16 + c] = f2bf(s[kt][j]);
        // PV
        s16x8 pa0 = *(const s16x8*)&Plds[wave][c][g * 8];
        s16x8 pa1 = *(const s16x8*)&Plds[wave][c][32 + g * 8];
#pragma unroll
        for (int n = 0; n < 4; n++) {
            s16x8 vb0 = *(const s16x8*)&Vt[n * 16 + c][g * 8];
            s16x8 vb1 = *(const s16x8*)&Vt[n * 16 + c][32 + g * 8];
            acc[n] = __builtin_amdgcn_mfma_f32_16x16x32_bf16(pa0, vb0, acc[n], 0, 0, 0);
            acc[n] = __builtin_amdgcn_mfma_f32_16x16x32_bf16(pa1, vb1, acc[n], 0, 0, 0);
        }
    }
    // epilogue: normalize and store bf16
#pragma unroll
    for (int j = 0; j < 4; j++) {
        float inv = 1.f / lr[j];
        size_t rbase = (size_t)(b * S + q0 + g * 4 + j) * 1024 + h * 64;
#pragma unroll
        for (int n = 0; n < 4; n++)
            o[rbase + n * 16 + c] = f2bf(acc[n][j] * inv);
    }
}

// ---------- host ----------
extern "C" void kernel_launch(void* const* d_in, const int* in_sizes, int n_in,
                              void* d_out, int out_size, void* d_ws, size_t ws_size,
                              hipStream_t stream)
{
    const float* x    = (const float*)d_in[0];
    // d_in[1] = causal mask (statically known; ignored)
    const float* Wq   = (const float*)d_in[2];  const float* bq = (const float*)d_in[3];
    const float* Wk   = (const float*)d_in[4];  const float* bk = (const float*)d_in[5];
    const float* Wv   = (const float*)d_in[6];  const float* bv = (const float*)d_in[7];
    const float* Wo   = (const float*)d_in[8];  const float* bo = (const float*)d_in[9];
    const float* W1   = (const float*)d_in[10]; const float* b1 = (const float*)d_in[11];
    const float* W2   = (const float*)d_in[12]; const float* b2 = (const float*)d_in[13];
    const float* ln1g = (const float*)d_in[14]; const float* ln1b = (const float*)d_in[15];
    const float* ln2g = (const float*)d_in[16]; const float* ln2b = (const float*)d_in[17];

    unsigned char* ws = (unsigned char*)d_ws;
    // ws layout (bytes); f1buf aliases qkvbuf+attnb (dead by FFN1)
    u16*   Wqkv_t = (u16*)(ws + 0);              //  6,291,456  bf16 [3072][1024]
    u16*   Wo_t   = (u16*)(ws + 6291456);        //  2,097,152  bf16 [1024][1024]
    u16*   W1_t   = (u16*)(ws + 8388608);        //  8,388,608  bf16 [4096][1024]
    u16*   W2_t   = (u16*)(ws + 16777216);       //  8,388,608  bf16 [1024][4096]
    float* bqkv   = (float*)(ws + 25165824);     //     12,288  f32  [3072]
    u16*   lnbuf  = (u16*)(ws + 25178112);       //  8,388,608  bf16 (ln1 then ln2)
    u16*   qkvbuf = (u16*)(ws + 33566720);       // 25,165,824  bf16 [4096][3072]
    u16*   attnb  = (u16*)(ws + 58732544);       //  8,388,608  bf16 [4096][1024]
    u16*   f1buf  = (u16*)(ws + 33566720);       // 33,554,432  bf16 [4096][4096]
    float* hbuf   = (float*)(ws + 67121152);     // 16,777,216  f32  [4096][1024]
    // total 83,898,368 bytes

    // weight transposes (f32 -> bf16) + bias concat
    transpose_f2b<<<dim3(32, 32), 256, 0, stream>>>(Wq, Wqkv_t,               1024, 1024);
    transpose_f2b<<<dim3(32, 32), 256, 0, stream>>>(Wk, Wqkv_t + 1024 * 1024, 1024, 1024);
    transpose_f2b<<<dim3(32, 32), 256, 0, stream>>>(Wv, Wqkv_t + 2048 * 1024, 1024, 1024);
    transpose_f2b<<<dim3(32, 32), 256, 0, stream>>>(Wo, Wo_t,                 1024, 1024);
    transpose_f2b<<<dim3(128, 32), 256, 0, stream>>>(W1, W1_t,                1024, 4096);
    transpose_f2b<<<dim3(32, 128), 256, 0, stream>>>(W2, W2_t,                4096, 1024);
    concat3<<<12, 256, 0, stream>>>(bq, bk, bv, bqkv);

    // ln1 -> fused QKV GEMM -> attention
    ln_k<<<1024, 256, 0, stream>>>(x, ln1g, ln1b, lnbuf);
    gemm_bt<0, false, false><<<dim3(24, 32), 256, 0, stream>>>(
        lnbuf, Wqkv_t, bqkv, nullptr, qkvbuf, 4096, 3072, 1024);
    attn_fwd<<<dim3(32, 32), 256, 0, stream>>>(qkvbuf, attnb);

    // h = x + attn @ Wo + bo  (f32)
    gemm_bt<2, false, true><<<dim3(8, 32), 256, 0, stream>>>(
        attnb, Wo_t, bo, x, hbuf, 4096, 1024, 1024);

    // ln2 -> FFN -> out (f32) with h residual
    ln_k<<<1024, 256, 0, stream>>>(hbuf, ln2g, ln2b, lnbuf);
    gemm_bt<0, true, false><<<dim3(32, 32), 256, 0, stream>>>(
        lnbuf, W1_t, b1, nullptr, f1buf, 4096, 4096, 1024);
    gemm_bt<2, false, true><<<dim3(8, 32), 256, 0, stream>>>(
        f1buf, W2_t, b2, hbuf, (float*)d_out, 4096, 1024, 4096);
}

// Round 3
// 431.444 us; speedup vs baseline: 1.1992x; 1.1992x over previous
//
#include <hip/hip_runtime.h>

typedef unsigned short u16;
typedef __attribute__((ext_vector_type(8))) short    s16x8;
typedef __attribute__((ext_vector_type(8))) unsigned short u16x8;
typedef __attribute__((ext_vector_type(4))) float    f32x4;

typedef __attribute__((address_space(1))) const void gvoid_c;
typedef __attribute__((address_space(3))) void       lvoid;

__device__ __forceinline__ float b2f(u16 x) {
    return __builtin_bit_cast(float, (unsigned)x << 16);
}
__device__ __forceinline__ u16 f2bf(float f) {
    unsigned u = __builtin_bit_cast(unsigned, f);
    return (u16)((u + 0x7FFFu + ((u >> 16) & 1u)) >> 16);
}
__device__ __forceinline__ void gld16(const void* g, void* l) {
    __builtin_amdgcn_global_load_lds((gvoid_c*)g, (lvoid*)l, 16, 0, 0);
}

// ---------- transpose + f32->bf16: in f32[R][C] -> out bf16[C][R] ----------
__global__ __launch_bounds__(256) void transpose_f2b(
    const float* __restrict__ in, u16* __restrict__ out, int R, int C)
{
    __shared__ u16 tile[32][33];
    int tx = threadIdx.x & 31, ty = threadIdx.x >> 5;  // 32 x 8
    int c0 = blockIdx.x * 32, r0 = blockIdx.y * 32;
#pragma unroll
    for (int i = 0; i < 32; i += 8)
        tile[ty + i][tx] = f2bf(in[(size_t)(r0 + ty + i) * C + c0 + tx]);
    __syncthreads();
#pragma unroll
    for (int i = 0; i < 32; i += 8)
        out[(size_t)(c0 + ty + i) * R + r0 + tx] = tile[tx][ty + i];
}

// ---------- bias concat [bq|bk|bv] (f32) ----------
__global__ void concat3(const float* a, const float* b, const float* c, float* o) {
    int i = blockIdx.x * blockDim.x + threadIdx.x;  // 3072
    o[i] = (i < 1024) ? a[i] : (i < 2048 ? b[i - 1024] : c[i - 2048]);
}

// ---------- LayerNorm: wave per row, D=1024; f32 in, bf16 out ----------
__global__ __launch_bounds__(256) void ln_k(
    const float* __restrict__ in, const float* __restrict__ gg,
    const float* __restrict__ bb, u16* __restrict__ out)
{
    const int D = 1024;
    int row  = blockIdx.x * 4 + (threadIdx.x >> 6);
    int lane = threadIdx.x & 63;
    const float* ip = in + (size_t)row * D;
    float v[16];
#pragma unroll
    for (int cc = 0; cc < 4; cc++) {
        f32x4 t = *(const f32x4*)(ip + cc * 256 + lane * 4);
#pragma unroll
        for (int i = 0; i < 4; i++) v[cc * 4 + i] = t[i];
    }
    float s1 = 0.f, s2 = 0.f;
#pragma unroll
    for (int i = 0; i < 16; i++) { s1 += v[i]; s2 += v[i] * v[i]; }
#pragma unroll
    for (int m = 1; m < 64; m <<= 1) { s1 += __shfl_xor(s1, m); s2 += __shfl_xor(s2, m); }
    float mu   = s1 * (1.f / 1024.f);
    float var  = s2 * (1.f / 1024.f) - mu * mu;
    float rstd = rsqrtf(var + 1e-5f);
#pragma unroll
    for (int cc = 0; cc < 4; cc++) {
        int e = cc * 256 + lane * 4;
        f32x4 gv = *(const f32x4*)(gg + e);
        f32x4 bv = *(const f32x4*)(bb + e);
        u16 o[4];
#pragma unroll
        for (int i = 0; i < 4; i++)
            o[i] = f2bf((v[cc * 4 + i] - mu) * rstd * gv[i] + bv[i]);
        *(__attribute__((ext_vector_type(4))) unsigned short*)(out + (size_t)row * D + e) =
            (__attribute__((ext_vector_type(4))) unsigned short){o[0], o[1], o[2], o[3]};
    }
}

// ---------- GEMM 128x128: C = A @ Bt^T + bias (+f32 res)(+relu) ----------
template <int RES, bool RELU, bool OUTF32>
__global__ __launch_bounds__(256) void gemm_bt(
    const u16* __restrict__ A, const u16* __restrict__ Bt,
    const float* __restrict__ bias, const float* __restrict__ res,
    void* __restrict__ out, int M, int N, int K)
{
    __shared__ u16 As[4096];  // [128][32]
    __shared__ u16 Bs[4096];
    int tid = threadIdx.x, wave = tid >> 6, lane = tid & 63;
    int g = lane >> 4, c = lane & 15;
    int wm = wave >> 1, wn = wave & 1;
    int m0 = blockIdx.y * 128, n0 = blockIdx.x * 128;

    f32x4 acc[4][4];
#pragma unroll
    for (int m = 0; m < 4; m++)
#pragma unroll
        for (int n = 0; n < 4; n++) acc[m][n] = (f32x4){0, 0, 0, 0};

    int ch0 = wave * 128 + lane, ch1 = ch0 + 64;
    const u16* Ag0 = A  + (size_t)(m0 + (ch0 >> 2)) * K + (ch0 & 3) * 8;
    const u16* Ag1 = A  + (size_t)(m0 + (ch1 >> 2)) * K + (ch1 & 3) * 8;
    const u16* Bg0 = Bt + (size_t)(n0 + (ch0 >> 2)) * K + (ch0 & 3) * 8;
    const u16* Bg1 = Bt + (size_t)(n0 + (ch1 >> 2)) * K + (ch1 & 3) * 8;
    u16* Al0 = &As[wave * 1024];
    u16* Al1 = &As[wave * 1024 + 512];
    u16* Bl0 = &Bs[wave * 1024];
    u16* Bl1 = &Bs[wave * 1024 + 512];

    for (int k0 = 0; k0 < K; k0 += 32) {
        __syncthreads();
        gld16(Ag0, Al0); gld16(Ag1, Al1);
        gld16(Bg0, Bl0); gld16(Bg1, Bl1);
        Ag0 += 32; Ag1 += 32; Bg0 += 32; Bg1 += 32;
        __syncthreads();
        s16x8 af[4], bfr[4];
#pragma unroll
        for (int m = 0; m < 4; m++)
            af[m] = *(const s16x8*)&As[(wm * 64 + m * 16 + c) * 32 + g * 8];
#pragma unroll
        for (int n = 0; n < 4; n++)
            bfr[n] = *(const s16x8*)&Bs[(wn * 64 + n * 16 + c) * 32 + g * 8];
#pragma unroll
        for (int m = 0; m < 4; m++)
#pragma unroll
            for (int n = 0; n < 4; n++)
                acc[m][n] = __builtin_amdgcn_mfma_f32_16x16x32_bf16(af[m], bfr[n], acc[m][n], 0, 0, 0);
    }

#pragma unroll
    for (int n = 0; n < 4; n++) {
        int col = n0 + wn * 64 + n * 16 + c;
        float bb = bias[col];
#pragma unroll
        for (int m = 0; m < 4; m++) {
#pragma unroll
            for (int j = 0; j < 4; j++) {
                int row = m0 + wm * 64 + m * 16 + g * 4 + j;
                float v = acc[m][n][j] + bb;
                if (RES == 2) v += res[(size_t)row * N + col];
                if (RELU) v = fmaxf(v, 0.f);
                if (OUTF32) ((float*)out)[(size_t)row * N + col] = v;
                else        ((u16*)out)[(size_t)row * N + col] = f2bf(v);
            }
        }
    }
}

// ---------- GEMM 128x64 (more blocks for narrow N) ----------
template <int RES, bool RELU, bool OUTF32>
__global__ __launch_bounds__(256) void gemm_bt_n64(
    const u16* __restrict__ A, const u16* __restrict__ Bt,
    const float* __restrict__ bias, const float* __restrict__ res,
    void* __restrict__ out, int M, int N, int K)
{
    __shared__ u16 As[4096];  // [128][32]
    __shared__ u16 Bs[2048];  // [64][32]
    int tid = threadIdx.x, wave = tid >> 6, lane = tid & 63;
    int g = lane >> 4, c = lane & 15;
    int wm = wave >> 1, wn = wave & 1;
    int m0 = blockIdx.y * 128, n0 = blockIdx.x * 64;

    f32x4 acc[4][2];
#pragma unroll
    for (int m = 0; m < 4; m++)
#pragma unroll
        for (int n = 0; n < 2; n++) acc[m][n] = (f32x4){0, 0, 0, 0};

    int ch0 = wave * 128 + lane, ch1 = ch0 + 64;  // A: 2 chunks/thread
    int chb = wave * 64 + lane;                   // B: 1 chunk/thread
    const u16* Ag0 = A  + (size_t)(m0 + (ch0 >> 2)) * K + (ch0 & 3) * 8;
    const u16* Ag1 = A  + (size_t)(m0 + (ch1 >> 2)) * K + (ch1 & 3) * 8;
    const u16* Bg0 = Bt + (size_t)(n0 + (chb >> 2)) * K + (chb & 3) * 8;
    u16* Al0 = &As[wave * 1024];
    u16* Al1 = &As[wave * 1024 + 512];
    u16* Bl0 = &Bs[wave * 512];

    for (int k0 = 0; k0 < K; k0 += 32) {
        __syncthreads();
        gld16(Ag0, Al0); gld16(Ag1, Al1);
        gld16(Bg0, Bl0);
        Ag0 += 32; Ag1 += 32; Bg0 += 32;
        __syncthreads();
        s16x8 af[4], bfr[2];
#pragma unroll
        for (int m = 0; m < 4; m++)
            af[m] = *(const s16x8*)&As[(wm * 64 + m * 16 + c) * 32 + g * 8];
#pragma unroll
        for (int n = 0; n < 2; n++)
            bfr[n] = *(const s16x8*)&Bs[(wn * 32 + n * 16 + c) * 32 + g * 8];
#pragma unroll
        for (int m = 0; m < 4; m++)
#pragma unroll
            for (int n = 0; n < 2; n++)
                acc[m][n] = __builtin_amdgcn_mfma_f32_16x16x32_bf16(af[m], bfr[n], acc[m][n], 0, 0, 0);
    }

#pragma unroll
    for (int n = 0; n < 2; n++) {
        int col = n0 + wn * 32 + n * 16 + c;
        float bb = bias[col];
#pragma unroll
        for (int m = 0; m < 4; m++) {
#pragma unroll
            for (int j = 0; j < 4; j++) {
                int row = m0 + wm * 64 + m * 16 + g * 4 + j;
                float v = acc[m][n][j] + bb;
                if (RES == 2) v += res[(size_t)row * N + col];
                if (RELU) v = fmaxf(v, 0.f);
                if (OUTF32) ((float*)out)[(size_t)row * N + col] = v;
                else        ((u16*)out)[(size_t)row * N + col] = f2bf(v);
            }
        }
    }
}

// ---------- V transpose: qkv V-cols -> vt[bh][d][s], XOR-swizzled per 64-kv tile ----------
// vt[bh][d][t0+e] = V[b, s = t0 + (e ^ ((d&7)*8)), h, d]
__global__ __launch_bounds__(256) void v_transpose(
    const u16* __restrict__ qkv, u16* __restrict__ vt)
{
    const int S = 2048, NC = 3072;
    __shared__ u16 tile[64][72];
    int st = blockIdx.x, bh = blockIdx.y, b = bh >> 4, h = bh & 15;
    int tid = threadIdx.x;
    int i = tid >> 3, cb8 = (tid & 7) * 8;
    const u16* src = qkv + (size_t)(b * S + st * 64) * NC + 2048 + h * 64;
    u16x8 a0 = *(const u16x8*)(src + (size_t)i * NC + cb8);
    u16x8 a1 = *(const u16x8*)(src + (size_t)(i + 32) * NC + cb8);
    *(u16x8*)&tile[i][cb8]      = a0;
    *(u16x8*)&tile[i + 32][cb8] = a1;
    __syncthreads();
    int d = tid >> 3, e8 = (tid & 7) * 8;
    int m = (d & 7) * 8;  // same for d and d+32
#pragma unroll
    for (int rr = 0; rr < 2; rr++) {
        int r = d + rr * 32;
        u16x8 o;
#pragma unroll
        for (int j = 0; j < 8; j++) o[j] = tile[(e8 ^ m) + j][r];
        *(u16x8*)(vt + ((size_t)bh * 64 + r) * 2048 + st * 64 + e8) = o;
    }
}

// ---------- flash attention (causal, load-balanced, LDS-staged K/V) ----------
// block = (qp, bh): processes q-tiles {31-qp, qp} -> uniform 33 KV-tile iters.
// K staged with XOR swizzle (source-side), V from pre-swizzled vt buffer.
__global__ __launch_bounds__(256) void attn_fwd2(
    const u16* __restrict__ qkv, const u16* __restrict__ vt,
    u16* __restrict__ o)
{
    const int S = 2048, NC = 3072;
    __shared__ u16 Ks[4096];          // [64][64] swizzled
    __shared__ u16 Vs[4096];          // [64][64] swizzled (V^T)
    __shared__ u16 Plds[4][16][72];
    int qp = blockIdx.x, bh = blockIdx.y, b = bh >> 4, h = bh & 15;
    int tid = threadIdx.x, wave = tid >> 6, lane = tid & 63;
    int g = lane >> 4, c = lane & 15;
    int sr = tid >> 3, scb8 = (tid & 7) * 8;
    int mS = (sr & 7) * 8;            // staging XOR mask (same for sr, sr+32)
    int mR = (c & 7) * 8;             // read XOR mask

    const u16* kbase = qkv + (size_t)b * S * NC + 1024 + h * 64;
    const u16* vbase = vt + (size_t)bh * 64 * 2048;

#pragma unroll 1
    for (int ph = 0; ph < 2; ph++) {
        int qt = ph ? qp : 31 - qp;
        int q0 = qt * 64 + wave * 16;
        const u16* qptr = qkv + (size_t)(b * S + q0 + c) * NC + h * 64;
        s16x8 qf0 = *(const s16x8*)(qptr + g * 8);
        s16x8 qf1 = *(const s16x8*)(qptr + 32 + g * 8);

        float mr[4], lr[4];
        f32x4 acc[4];
#pragma unroll
        for (int j = 0; j < 4; j++) { mr[j] = -1e30f; lr[j] = 0.f; }
#pragma unroll
        for (int n = 0; n < 4; n++) acc[n] = (f32x4){0, 0, 0, 0};

        int ntiles = qt + 1;
        for (int t = 0; t < ntiles; t++) {
            int t0 = t * 64;
            __syncthreads();  // prev-tile reads done
            gld16(kbase + (size_t)(t0 + sr)      * NC + (scb8 ^ mS), &Ks[wave * 512]);
            gld16(kbase + (size_t)(t0 + sr + 32) * NC + (scb8 ^ mS), &Ks[2048 + wave * 512]);
            gld16(vbase + (size_t)sr        * 2048 + t0 + scb8, &Vs[wave * 512]);
            gld16(vbase + (size_t)(sr + 32) * 2048 + t0 + scb8, &Vs[2048 + wave * 512]);
            __syncthreads();  // staging complete (vmcnt drained by barrier)

            // QK^T from LDS
            f32x4 s[4];
#pragma unroll
            for (int kt = 0; kt < 4; kt++) {
                int r = kt * 16 + c;
                s16x8 kf0 = *(const s16x8*)&Ks[r * 64 + ((g * 8) ^ mR)];
                s16x8 kf1 = *(const s16x8*)&Ks[r * 64 + ((32 + g * 8) ^ mR)];
                f32x4 sv = (f32x4){0, 0, 0, 0};
                sv = __builtin_amdgcn_mfma_f32_16x16x32_bf16(qf0, kf0, sv, 0, 0, 0);
                sv = __builtin_amdgcn_mfma_f32_16x16x32_bf16(qf1, kf1, sv, 0, 0, 0);
                s[kt] = sv;
            }
            // scale + causal mask
#pragma unroll
            for (int kt = 0; kt < 4; kt++) {
                int kcol = t0 + kt * 16 + c;
#pragma unroll
                for (int j = 0; j < 4; j++) {
                    int qrow = q0 + g * 4 + j;
                    s[kt][j] = (kcol <= qrow) ? s[kt][j] * 0.125f : -1e30f;
                }
            }
            // online softmax (16-lane row groups)
#pragma unroll
            for (int j = 0; j < 4; j++) {
                float tm = fmaxf(fmaxf(s[0][j], s[1][j]), fmaxf(s[2][j], s[3][j]));
#pragma unroll
                for (int m = 1; m < 16; m <<= 1) tm = fmaxf(tm, __shfl_xor(tm, m));
                float mnew = fmaxf(mr[j], tm);
                float corr = __expf(mr[j] - mnew);
                float rs = 0.f;
#pragma unroll
                for (int kt = 0; kt < 4; kt++) { float p = __expf(s[kt][j] - mnew); s[kt][j] = p; rs += p; }
#pragma unroll
                for (int m = 1; m < 16; m <<= 1) rs += __shfl_xor(rs, m);
                lr[j] = lr[j] * corr + rs;
                mr[j] = mnew;
#pragma unroll
                for (int n = 0; n < 4; n++) acc[n][j] *= corr;
            }
            // P -> LDS (bf16, wave-local)
#pragma unroll
            for (int kt = 0; kt < 4; kt++)
#pragma unroll
                for (int j = 0; j < 4; j++)
                    Plds[wave][g * 4 + j][kt * 16 + c] = f2bf(s[kt][j]);
            // PV
            s16x8 pa0 = *(const s16x8*)&Plds[wave][c][g * 8];
            s16x8 pa1 = *(const s16x8*)&Plds[wave][c][32 + g * 8];
#pragma unroll
            for (int n = 0; n < 4; n++) {
                int r = n * 16 + c;
                s16x8 vb0 = *(const s16x8*)&Vs[r * 64 + ((g * 8) ^ mR)];
                s16x8 vb1 = *(const s16x8*)&Vs[r * 64 + ((32 + g * 8) ^ mR)];
                acc[n] = __builtin_amdgcn_mfma_f32_16x16x32_bf16(pa0, vb0, acc[n], 0, 0, 0);
                acc[n] = __builtin_amdgcn_mfma_f32_16x16x32_bf16(pa1, vb1, acc[n], 0, 0, 0);
            }
        }
        // epilogue: normalize and store bf16
#pragma unroll
        for (int j = 0; j < 4; j++) {
            float inv = 1.f / lr[j];
            size_t rbase = (size_t)(b * S + q0 + g * 4 + j) * 1024 + h * 64;
#pragma unroll
            for (int n = 0; n < 4; n++)
                o[rbase + n * 16 + c] = f2bf(acc[n][j] * inv);
        }
    }
}

// ---------- host ----------
extern "C" void kernel_launch(void* const* d_in, const int* in_sizes, int n_in,
                              void* d_out, int out_size, void* d_ws, size_t ws_size,
                              hipStream_t stream)
{
    const float* x    = (const float*)d_in[0];
    // d_in[1] = causal mask (statically known; ignored)
    const float* Wq   = (const float*)d_in[2];  const float* bq = (const float*)d_in[3];
    const float* Wk   = (const float*)d_in[4];  const float* bk = (const float*)d_in[5];
    const float* Wv   = (const float*)d_in[6];  const float* bv = (const float*)d_in[7];
    const float* Wo   = (const float*)d_in[8];  const float* bo = (const float*)d_in[9];
    const float* W1   = (const float*)d_in[10]; const float* b1 = (const float*)d_in[11];
    const float* W2   = (const float*)d_in[12]; const float* b2 = (const float*)d_in[13];
    const float* ln1g = (const float*)d_in[14]; const float* ln1b = (const float*)d_in[15];
    const float* ln2g = (const float*)d_in[16]; const float* ln2b = (const float*)d_in[17];

    unsigned char* ws = (unsigned char*)d_ws;
    // ws layout; f1buf aliases qkvbuf+attnb (dead by FFN1); vtbuf aliases hbuf
    // (vtbuf live [v_transpose, attn]; hbuf live [Wo-GEMM, end] - disjoint)
    u16*   Wqkv_t = (u16*)(ws + 0);              //  6,291,456  bf16 [3072][1024]
    u16*   Wo_t   = (u16*)(ws + 6291456);        //  2,097,152  bf16 [1024][1024]
    u16*   W1_t   = (u16*)(ws + 8388608);        //  8,388,608  bf16 [4096][1024]
    u16*   W2_t   = (u16*)(ws + 16777216);       //  8,388,608  bf16 [1024][4096]
    float* bqkv   = (float*)(ws + 25165824);     //     12,288  f32  [3072]
    u16*   lnbuf  = (u16*)(ws + 25178112);       //  8,388,608  bf16
    u16*   qkvbuf = (u16*)(ws + 33566720);       // 25,165,824  bf16 [4096][3072]
    u16*   attnb  = (u16*)(ws + 58732544);       //  8,388,608  bf16 [4096][1024]
    u16*   f1buf  = (u16*)(ws + 33566720);       // 33,554,432  bf16 [4096][4096]
    float* hbuf   = (float*)(ws + 67121152);     // 16,777,216  f32  [4096][1024]
    u16*   vtbuf  = (u16*)(ws + 67121152);       //  8,388,608  bf16 [32][64][2048]
    // total 83,898,368 bytes

    // weight transposes (f32 -> bf16) + bias concat
    transpose_f2b<<<dim3(32, 32), 256, 0, stream>>>(Wq, Wqkv_t,               1024, 1024);
    transpose_f2b<<<dim3(32, 32), 256, 0, stream>>>(Wk, Wqkv_t + 1024 * 1024, 1024, 1024);
    transpose_f2b<<<dim3(32, 32), 256, 0, stream>>>(Wv, Wqkv_t + 2048 * 1024, 1024, 1024);
    transpose_f2b<<<dim3(32, 32), 256, 0, stream>>>(Wo, Wo_t,                 1024, 1024);
    transpose_f2b<<<dim3(128, 32), 256, 0, stream>>>(W1, W1_t,                1024, 4096);
    transpose_f2b<<<dim3(32, 128), 256, 0, stream>>>(W2, W2_t,                4096, 1024);
    concat3<<<12, 256, 0, stream>>>(bq, bk, bv, bqkv);

    // ln1 -> fused QKV GEMM -> V transpose -> attention
    ln_k<<<1024, 256, 0, stream>>>(x, ln1g, ln1b, lnbuf);
    gemm_bt<0, false, false><<<dim3(24, 32), 256, 0, stream>>>(
        lnbuf, Wqkv_t, bqkv, nullptr, qkvbuf, 4096, 3072, 1024);
    v_transpose<<<dim3(32, 32), 256, 0, stream>>>(qkvbuf, vtbuf);
    attn_fwd2<<<dim3(16, 32), 256, 0, stream>>>(qkvbuf, vtbuf, attnb);

    // h = x + attn @ Wo + bo  (f32)
    gemm_bt_n64<2, false, true><<<dim3(16, 32), 256, 0, stream>>>(
        attnb, Wo_t, bo, x, hbuf, 4096, 1024, 1024);

    // ln2 -> FFN -> out (f32) with h residual
    ln_k<<<1024, 256, 0, stream>>>(hbuf, ln2g, ln2b, lnbuf);
    gemm_bt<0, true, false><<<dim3(32, 32), 256, 0, stream>>>(
        lnbuf, W1_t, b1, nullptr, f1buf, 4096, 4096, 1024);
    gemm_bt_n64<2, false, true><<<dim3(16, 32), 256, 0, stream>>>(
        f1buf, W2_t, b2, hbuf, (float*)d_out, 4096, 1024, 4096);
}